// Round 7
// baseline (113.956 us; speedup 1.0000x reference)
//
#include <hip/hip_runtime.h>
#include <hip/hip_bf16.h>
#include <stdint.h>

typedef unsigned int u32;

#define BATCH 64
#define ROOT 128
#define NLEAF 7
#define LHEAD 4
#define HDIM 128
#define NNODES 1024
#define OUTROWS 1025
#define NREL1 65          // NUM_REL + 1
#define PSTR 132          // padded LDS row stride (dwords)

typedef __attribute__((ext_vector_type(8))) short bf16x8;
typedef __attribute__((ext_vector_type(4))) float f32x4;

// Per-relation precomputed (rewritten every launch — idempotent):
//   g_U = M^T r_even, g_V = M^T r_odd (fp32)
//   g_Mfrag = M as bf16 in MFMA A-fragment order:
//     uint4 index per rel: (rt*4 + kt)*64 + lane
//     holds M[i=rt*16+(lane&15)][k=kt*32+(lane>>4)*8 + 0..7]
__device__ float g_U[NREL1 * HDIM];
__device__ float g_V[NREL1 * HDIM];
__device__ u32   g_Mfrag[NREL1 * 8192];

static __device__ __forceinline__ u32 rne_bf16(float f) {
    u32 u = __builtin_bit_cast(u32, f);
    return (u + 0x7fffu + ((u >> 16) & 1u)) >> 16;
}
static __device__ __forceinline__ u32 pack_bf16(float a, float b) {
    return rne_bf16(a) | (rne_bf16(b) << 16);
}

// ---------------------------------------------------------------------------
// prep_kernel: grid (65, 8), block 256.  (unchanged from round 6 — passed)
//  part 0..3 : pack one quarter of M[rel] into g_Mfrag (A-fragment order)
//  part 4..7 : U/V for one 32-wide j-strip, i split 8 ways + LDS tree reduce
// ---------------------------------------------------------------------------
__global__ void prep_kernel(const float* __restrict__ rel_mat,
                            const float* __restrict__ rel_emb) {
    int rel = blockIdx.x;
    int part = blockIdx.y;
    const float* M = rel_mat + (size_t)rel * HDIM * HDIM;
    __shared__ float red_u[8][32], red_v[8][32];

    if (part < 4) {
        u32* dst = &g_Mfrag[(size_t)rel * 8192];
        #pragma unroll
        for (int q = 0; q < 8; ++q) {
            int o = part * 2048 + q * 256 + threadIdx.x;   // 0..8191 dwords
            int r  = o >> 10;
            int t  = (o >> 8) & 3;
            int ln = (o >> 2) & 63;
            int dw = o & 3;
            int i = r * 16 + (ln & 15);
            int j = t * 32 + ((ln >> 4) << 3) + dw * 2;
            dst[o] = pack_bf16(M[i * HDIM + j], M[i * HDIM + j + 1]);
        }
    } else {
        int p = part - 4;
        int jj = threadIdx.x & 31, s = threadIdx.x >> 5;   // 32 j × 8 i-slices
        int j = p * 32 + jj;
        const float* r = rel_emb + (size_t)rel * 2 * HDIM;
        float u = 0.f, v = 0.f;
        #pragma unroll
        for (int ii = 0; ii < 16; ++ii) {
            int i = s * 16 + ii;
            float m = M[i * HDIM + j];
            u += r[2 * i] * m;
            v += r[2 * i + 1] * m;
        }
        red_u[s][jj] = u; red_v[s][jj] = v;
        __syncthreads();
        if (s == 0) {
            float su = 0.f, sv = 0.f;
            #pragma unroll
            for (int q = 0; q < 8; ++q) { su += red_u[q][jj]; sv += red_v[q][jj]; }
            g_U[rel * HDIM + j] = su;
            g_V[rel * HDIM + j] = sv;
        }
    }
}

// ---------------------------------------------------------------------------
// triple_kernel: grid (32, 64), 4 waves/block, ONE WAVE = ONE TRIPLE, zero
// __syncthreads. Round-7: wave-uniform values forced scalar (readfirstlane)
// so tokens come in via s_load at wave start; he_s/MhT share one LDS buffer
// (wave-sequential lifetimes); epilogue MhT reads hoisted.
// ---------------------------------------------------------------------------
__global__ __launch_bounds__(256) void triple_kernel(
    const int* __restrict__ tok,
    const int* __restrict__ leaf_rel,
    const float* __restrict__ atom,
    const float* __restrict__ gtok,
    float* __restrict__ out)
{
    int g = blockIdx.x;                 // 4 roots per block
    int b = blockIdx.y;
    int tid = threadIdx.x;
    int wave = __builtin_amdgcn_readfirstlane(tid >> 6);
    int lane = tid & 63;
    int rn = g * 4 + wave;              // wave-uniform scalar

    // one buffer, two lifetimes per wave: phase 1 = he rows (B-frag relayout),
    // phase 2 = MhT (transposed MFMA output). No overlap in program order.
    __shared__ __align__(16) float scr[4][LHEAD][PSTR];

    int rel = __builtin_amdgcn_readfirstlane(leaf_rel[b * ROOT + rn]);

    // ---- tokens: all indices wave-uniform -> s_load into SGPRs ----
    int htok[LHEAD], ttok[NLEAF];
    #pragma unroll
    for (int l = 0; l < LHEAD; ++l) {
        int hp = rn + l; if (hp > ROOT - 1) hp = ROOT - 1;     // torch clip
        htok[l] = tok[b * NNODES + hp];
    }
    #pragma unroll
    for (int t = 0; t < NLEAF; ++t)
        ttok[t] = tok[b * NNODES + ROOT + rn * NLEAF + t];

    // ---- each atom row ONCE into registers (22 independent loads, SGPR base) ----
    float he_lo[LHEAD], he_hi[LHEAD], te_lo[NLEAF], te_hi[NLEAF];
    #pragma unroll
    for (int l = 0; l < LHEAD; ++l) {
        const float* r = atom + (size_t)htok[l] * HDIM;
        he_lo[l] = r[lane]; he_hi[l] = r[lane + 64];
    }
    #pragma unroll
    for (int t = 0; t < NLEAF; ++t) {
        const float* r = atom + (size_t)ttok[t] * HDIM;
        te_lo[t] = r[lane]; te_hi[t] = r[lane + 64];
    }

    const float* U = &g_U[rel * HDIM];
    const float* V = &g_V[rel * HDIM];
    float u_lo = U[lane], u_hi = U[lane + 64];
    float v_lo = V[lane], v_hi = V[lane + 64];

    // ---- he -> LDS (phase 1: B-frag cross-lane relayout) ----
    #pragma unroll
    for (int l = 0; l < LHEAD; ++l) {
        scr[wave][l][lane]      = he_lo[l];
        scr[wave][l][lane + 64] = he_hi[l];
    }

    // ---- root row (= he[0] regs) + graph token: early, latency filler ----
    size_t bbase = (size_t)b * OUTROWS * HDIM;
    out[bbase + (size_t)(1 + rn) * HDIM + lane]      = he_lo[0];
    out[bbase + (size_t)(1 + rn) * HDIM + lane + 64] = he_hi[0];
    if (g == 0 && wave == 0) {
        out[bbase + lane]      = gtok[lane];
        out[bbase + lane + 64] = gtok[lane + 64];
    }

    // ---- 11 dots; xor-butterfly leaves result in ALL lanes ----
    float a_r[NLEAF], b_r[LHEAD];
    #pragma unroll
    for (int t = 0; t < NLEAF; ++t) {
        float p = u_lo * te_lo[t] + u_hi * te_hi[t];
        #pragma unroll
        for (int m = 32; m > 0; m >>= 1) p += __shfl_xor(p, m, 64);
        a_r[t] = p;
    }
    #pragma unroll
    for (int l = 0; l < LHEAD; ++l) {
        float p = v_lo * he_lo[l] + v_hi * he_hi[l];
        #pragma unroll
        for (int m = 32; m > 0; m >>= 1) p += __shfl_xor(p, m, 64);
        b_r[l] = p;
    }

    // ---- B-fragments from scr phase 1 (b128 reads, padded stride) ----
    int nn = lane & 15;                  // MFMA col; head = nn&3 (cols 4..15 junk)
    int kb = (lane >> 4) << 3;           // k-chunk base in 32-wide k-tile
    uint4 bfr[4];
    #pragma unroll
    for (int t = 0; t < 4; ++t) {
        const float* h = &scr[wave][nn & 3][t * 32 + kb];
        float4 f0 = *(const float4*)h;
        float4 f1 = *(const float4*)(h + 4);
        bfr[t].x = pack_bf16(f0.x, f0.y);
        bfr[t].y = pack_bf16(f0.z, f0.w);
        bfr[t].z = pack_bf16(f1.x, f1.y);
        bfr[t].w = pack_bf16(f1.z, f1.w);
    }

    // ---- MFMA: Mh = M·he^T, 8 row-tiles; scr becomes phase 2 (MhT) ----
    const uint4* Mf = ((const uint4*)g_Mfrag) + (size_t)rel * 2048;
    #pragma unroll
    for (int rt = 0; rt < 8; ++rt) {
        f32x4 acc = {0.f, 0.f, 0.f, 0.f};
        #pragma unroll
        for (int kt = 0; kt < 4; ++kt) {
            uint4 afr = Mf[(rt * 4 + kt) * 64 + lane];
            acc = __builtin_amdgcn_mfma_f32_16x16x32_bf16(
                      __builtin_bit_cast(bf16x8, afr),
                      __builtin_bit_cast(bf16x8, bfr[kt]), acc, 0, 0, 0);
        }
        if (nn < LHEAD) {                       // D: col=lane&15, row=(lane>>4)*4+reg
            int row0 = rt * 16 + ((lane >> 4) << 2);
            *(float4*)&scr[wave][nn][row0] = make_float4(acc[0], acc[1], acc[2], acc[3]);
        }
    }

    // ---- epilogue: hoist MhT reads (8 ds_read), then 7 tails from regs ----
    float mh_lo[LHEAD], mh_hi[LHEAD];
    #pragma unroll
    for (int l = 0; l < LHEAD; ++l) {
        mh_lo[l] = scr[wave][l][lane];
        mh_hi[l] = scr[wave][l][lane + 64];
    }
    size_t obase = bbase + (size_t)(1 + ROOT + rn * NLEAF) * HDIM;
    #pragma unroll
    for (int t = 0; t < NLEAF; ++t) {
        float sc[LHEAD]; float mx = -1e30f;
        #pragma unroll
        for (int l = 0; l < LHEAD; ++l) {
            float x = a_r[t] + b_r[l];
            x = (x >= 0.f) ? x : 0.01f * x;          // leaky_relu 0.01
            sc[l] = x; mx = fmaxf(mx, x);
        }
        float sum = 0.f;
        #pragma unroll
        for (int l = 0; l < LHEAD; ++l) { sc[l] = __expf(sc[l] - mx); sum += sc[l]; }
        float inv = 1.f / sum;
        float r0 = te_lo[t], r1 = te_hi[t];
        #pragma unroll
        for (int l = 0; l < LHEAD; ++l) {
            float al = sc[l] * inv;
            r0 += al * mh_lo[l];
            r1 += al * mh_hi[l];
        }
        out[obase + t * HDIM + lane]      = r0;
        out[obase + t * HDIM + lane + 64] = r1;
    }
}

// ---------------------------------------------------------------------------
extern "C" void kernel_launch(void* const* d_in, const int* in_sizes, int n_in,
                              void* d_out, int out_size, void* d_ws, size_t ws_size,
                              hipStream_t stream) {
    (void)in_sizes; (void)n_in; (void)out_size; (void)d_ws; (void)ws_size;
    const int* tok       = (const int*)d_in[0];     // [B,1024,1] int32
    const int* leaf_rel  = (const int*)d_in[1];     // [B,128]    int32
    // d_in[2] = head_lengths: unused by the reference body
    const float* atom    = (const float*)d_in[3];   // [30000,128] fp32
    const float* rel_mat = (const float*)d_in[4];   // [65,128*128] fp32
    const float* rel_emb = (const float*)d_in[5];   // [65,256] fp32
    const float* gtok    = (const float*)d_in[6];   // [1,128] fp32
    float* out = (float*)d_out;                     // [64,1025,128] fp32

    dim3 pgrid(NREL1, 8);
    prep_kernel<<<pgrid, 256, 0, stream>>>(rel_mat, rel_emb);

    dim3 grid(ROOT / 4, BATCH);
    triple_kernel<<<grid, 256, 0, stream>>>(tok, leaf_rel, atom, gtok, out);
}

// Round 8
// 111.572 us; speedup vs baseline: 1.0214x; 1.0214x over previous
//
#include <hip/hip_runtime.h>
#include <hip/hip_bf16.h>
#include <stdint.h>

typedef unsigned int u32;

#define BATCH 64
#define ROOT 128
#define NLEAF 7
#define LHEAD 4
#define HDIM 128
#define NNODES 1024
#define OUTROWS 1025
#define NREL1 65          // NUM_REL + 1
#define PSTR 132          // padded LDS row stride (dwords): 16B-aligned, de-conflicted

typedef __attribute__((ext_vector_type(8))) short bf16x8;
typedef __attribute__((ext_vector_type(4))) float f32x4;

// Per-relation precomputed (rewritten every launch — idempotent):
//   g_U = M^T r_even, g_V = M^T r_odd (fp32)
//   g_Mfrag = M as bf16 in MFMA A-fragment order:
//     uint4 index per rel: (rt*4 + kt)*64 + lane
//     holds M[i=rt*16+(lane&15)][k=kt*32+(lane>>4)*8 + 0..7]
__device__ float g_U[NREL1 * HDIM];
__device__ float g_V[NREL1 * HDIM];
__device__ u32   g_Mfrag[NREL1 * 8192];

static __device__ __forceinline__ u32 rne_bf16(float f) {
    u32 u = __builtin_bit_cast(u32, f);
    return (u + 0x7fffu + ((u >> 16) & 1u)) >> 16;
}
static __device__ __forceinline__ u32 pack_bf16(float a, float b) {
    return rne_bf16(a) | (rne_bf16(b) << 16);
}

// ---------------------------------------------------------------------------
// prep_kernel: grid (65, 8), block 256.
//  part 0..3 : pack one quarter of M[rel] into g_Mfrag (A-fragment order)
//  part 4..7 : U/V for one 32-wide j-strip, i split 8 ways + LDS tree reduce
// ---------------------------------------------------------------------------
__global__ void prep_kernel(const float* __restrict__ rel_mat,
                            const float* __restrict__ rel_emb) {
    int rel = blockIdx.x;
    int part = blockIdx.y;
    const float* M = rel_mat + (size_t)rel * HDIM * HDIM;
    __shared__ float red_u[8][32], red_v[8][32];

    if (part < 4) {
        u32* dst = &g_Mfrag[(size_t)rel * 8192];
        #pragma unroll
        for (int q = 0; q < 8; ++q) {
            int o = part * 2048 + q * 256 + threadIdx.x;   // 0..8191 dwords
            int r  = o >> 10;
            int t  = (o >> 8) & 3;
            int ln = (o >> 2) & 63;
            int dw = o & 3;
            int i = r * 16 + (ln & 15);
            int j = t * 32 + ((ln >> 4) << 3) + dw * 2;
            dst[o] = pack_bf16(M[i * HDIM + j], M[i * HDIM + j + 1]);
        }
    } else {
        int p = part - 4;
        int jj = threadIdx.x & 31, s = threadIdx.x >> 5;   // 32 j × 8 i-slices
        int j = p * 32 + jj;
        const float* r = rel_emb + (size_t)rel * 2 * HDIM;
        float u = 0.f, v = 0.f;
        #pragma unroll
        for (int ii = 0; ii < 16; ++ii) {
            int i = s * 16 + ii;
            float m = M[i * HDIM + j];
            u += r[2 * i] * m;
            v += r[2 * i + 1] * m;
        }
        red_u[s][jj] = u; red_v[s][jj] = v;
        __syncthreads();
        if (s == 0) {
            float su = 0.f, sv = 0.f;
            #pragma unroll
            for (int q = 0; q < 8; ++q) { su += red_u[q][jj]; sv += red_v[q][jj]; }
            g_U[rel * HDIM + j] = su;
            g_V[rel * HDIM + j] = sv;
        }
    }
}

// ---------------------------------------------------------------------------
// triple_kernel: grid (32, 64), 4 waves/block, ONE WAVE = ONE TRIPLE, zero
// __syncthreads. Each atom row loaded from global exactly once into regs:
//   te_lo/hi[7], he_lo/hi[4]  (dot layout == epilogue layout; he[0] == root row)
// Tokens broadcast lane->all via __shfl const-lane (v_readlane, no LDS).
// LDS only for: he B-frag relayout + MhT transpose (padded stride 132).
// (Round-8: verbatim revert to the best-measured round-6 configuration;
//  round-7's scalarization bundle was within noise / slightly negative.)
// ---------------------------------------------------------------------------
__global__ __launch_bounds__(256) void triple_kernel(
    const int* __restrict__ tok,
    const int* __restrict__ leaf_rel,
    const float* __restrict__ atom,
    const float* __restrict__ gtok,
    float* __restrict__ out)
{
    int g = blockIdx.x;                 // 4 roots per block
    int b = blockIdx.y;
    int tid = threadIdx.x;
    int wave = tid >> 6, lane = tid & 63;
    int rn = g * 4 + wave;

    __shared__ __align__(16) float he_s[4][LHEAD][PSTR];   // [wave][l][j]
    __shared__ __align__(16) float MhT[4][LHEAD][PSTR];    // [wave][l][i]

    int rel = leaf_rel[b * ROOT + rn];  // wave-uniform

    // ---- tokens: lanes 0..10 load, broadcast via const-lane shfl ----
    int tokidx = 0;
    if (lane < LHEAD + NLEAF) {
        int pos;
        if (lane < LHEAD) { int hp = rn + lane; if (hp > ROOT - 1) hp = ROOT - 1; pos = hp; }
        else              pos = ROOT + rn * NLEAF + (lane - LHEAD);
        tokidx = tok[b * NNODES + pos];
    }
    int htok[LHEAD], ttok[NLEAF];
    #pragma unroll
    for (int l = 0; l < LHEAD; ++l) htok[l] = __shfl(tokidx, l, 64);
    #pragma unroll
    for (int t = 0; t < NLEAF; ++t) ttok[t] = __shfl(tokidx, LHEAD + t, 64);

    // ---- each atom row ONCE into registers (11 x 2 independent loads) ----
    float he_lo[LHEAD], he_hi[LHEAD], te_lo[NLEAF], te_hi[NLEAF];
    #pragma unroll
    for (int l = 0; l < LHEAD; ++l) {
        const float* r = atom + (size_t)htok[l] * HDIM;
        he_lo[l] = r[lane]; he_hi[l] = r[lane + 64];
    }
    #pragma unroll
    for (int t = 0; t < NLEAF; ++t) {
        const float* r = atom + (size_t)ttok[t] * HDIM;
        te_lo[t] = r[lane]; te_hi[t] = r[lane + 64];
    }

    const float* U = &g_U[rel * HDIM];
    const float* V = &g_V[rel * HDIM];
    float u_lo = U[lane], u_hi = U[lane + 64];
    float v_lo = V[lane], v_hi = V[lane + 64];

    // ---- he -> LDS (for B-frag cross-lane relayout); conflict-free writes ----
    #pragma unroll
    for (int l = 0; l < LHEAD; ++l) {
        he_s[wave][l][lane]      = he_lo[l];
        he_s[wave][l][lane + 64] = he_hi[l];
    }

    // ---- 11 dots; xor-butterfly leaves the result in ALL lanes (no LDS) ----
    float a_r[NLEAF], b_r[LHEAD];
    #pragma unroll
    for (int t = 0; t < NLEAF; ++t) {
        float p = u_lo * te_lo[t] + u_hi * te_hi[t];
        #pragma unroll
        for (int m = 32; m > 0; m >>= 1) p += __shfl_xor(p, m, 64);
        a_r[t] = p;
    }
    #pragma unroll
    for (int l = 0; l < LHEAD; ++l) {
        float p = v_lo * he_lo[l] + v_hi * he_hi[l];
        #pragma unroll
        for (int m = 32; m > 0; m >>= 1) p += __shfl_xor(p, m, 64);
        b_r[l] = p;
    }

    // ---- B-fragments from he_s (b128 reads, padded stride) ----
    int nn = lane & 15;                  // MFMA col; head = nn&3 (cols 4..15 junk, never read)
    int kb = (lane >> 4) << 3;           // k-chunk base in 32-wide k-tile
    uint4 bfr[4];
    #pragma unroll
    for (int t = 0; t < 4; ++t) {
        const float* h = &he_s[wave][nn & 3][t * 32 + kb];
        float4 f0 = *(const float4*)h;
        float4 f1 = *(const float4*)(h + 4);
        bfr[t].x = pack_bf16(f0.x, f0.y);
        bfr[t].y = pack_bf16(f0.z, f0.w);
        bfr[t].z = pack_bf16(f1.x, f1.y);
        bfr[t].w = pack_bf16(f1.z, f1.w);
    }

    // ---- MFMA: Mh = M·he^T, 8 row-tiles, rt-sequential acc (4 VGPRs live) ----
    const uint4* Mf = ((const uint4*)g_Mfrag) + (size_t)rel * 2048;
    #pragma unroll
    for (int rt = 0; rt < 8; ++rt) {
        f32x4 acc = {0.f, 0.f, 0.f, 0.f};
        #pragma unroll
        for (int kt = 0; kt < 4; ++kt) {
            uint4 afr = Mf[(rt * 4 + kt) * 64 + lane];
            acc = __builtin_amdgcn_mfma_f32_16x16x32_bf16(
                      __builtin_bit_cast(bf16x8, afr),
                      __builtin_bit_cast(bf16x8, bfr[kt]), acc, 0, 0, 0);
        }
        if (nn < LHEAD) {                       // D: col=lane&15, row=(lane>>4)*4+reg
            int row0 = rt * 16 + ((lane >> 4) << 2);
            *(float4*)&MhT[wave][nn][row0] = make_float4(acc[0], acc[1], acc[2], acc[3]);
        }
    }

    // ---- root row (= he[0] regs) + graph token ----
    size_t bbase = (size_t)b * OUTROWS * HDIM;
    out[bbase + (size_t)(1 + rn) * HDIM + lane]      = he_lo[0];
    out[bbase + (size_t)(1 + rn) * HDIM + lane + 64] = he_hi[0];
    if (g == 0 && wave == 0) {
        out[bbase + lane]      = gtok[lane];
        out[bbase + lane + 64] = gtok[lane + 64];
    }

    // ---- epilogue: per tail, alpha in regs (uniform), te from regs ----
    size_t obase = bbase + (size_t)(1 + ROOT + rn * NLEAF) * HDIM;
    #pragma unroll
    for (int t = 0; t < NLEAF; ++t) {
        float sc[LHEAD]; float mx = -1e30f;
        #pragma unroll
        for (int l = 0; l < LHEAD; ++l) {
            float x = a_r[t] + b_r[l];
            x = (x >= 0.f) ? x : 0.01f * x;          // leaky_relu 0.01
            sc[l] = x; mx = fmaxf(mx, x);
        }
        float sum = 0.f;
        #pragma unroll
        for (int l = 0; l < LHEAD; ++l) { sc[l] = __expf(sc[l] - mx); sum += sc[l]; }
        float inv = 1.f / sum;
        float r0 = te_lo[t], r1 = te_hi[t];
        #pragma unroll
        for (int l = 0; l < LHEAD; ++l) {
            float al = sc[l] * inv;
            r0 += al * MhT[wave][l][lane];
            r1 += al * MhT[wave][l][lane + 64];
        }
        out[obase + t * HDIM + lane]      = r0;
        out[obase + t * HDIM + lane + 64] = r1;
    }
}

// ---------------------------------------------------------------------------
extern "C" void kernel_launch(void* const* d_in, const int* in_sizes, int n_in,
                              void* d_out, int out_size, void* d_ws, size_t ws_size,
                              hipStream_t stream) {
    (void)in_sizes; (void)n_in; (void)out_size; (void)d_ws; (void)ws_size;
    const int* tok       = (const int*)d_in[0];     // [B,1024,1] int32
    const int* leaf_rel  = (const int*)d_in[1];     // [B,128]    int32
    // d_in[2] = head_lengths: unused by the reference body
    const float* atom    = (const float*)d_in[3];   // [30000,128] fp32
    const float* rel_mat = (const float*)d_in[4];   // [65,128*128] fp32
    const float* rel_emb = (const float*)d_in[5];   // [65,256] fp32
    const float* gtok    = (const float*)d_in[6];   // [1,128] fp32
    float* out = (float*)d_out;                     // [64,1025,128] fp32

    dim3 pgrid(NREL1, 8);
    prep_kernel<<<pgrid, 256, 0, stream>>>(rel_mat, rel_emb);

    dim3 grid(ROOT / 4, BATCH);
    triple_kernel<<<grid, 256, 0, stream>>>(tok, leaf_rel, atom, gtok, out);
}